// Round 2
// baseline (113.010 us; speedup 1.0000x reference)
//
#include <hip/hip_runtime.h>

// out[pos, e] = W[e, tokens[pos]] — embedding gather, reorganized as a
// vocab-strip scatter so concurrent lanes cover ADJACENT vocab indices:
// needed elements share 128B lines (~92% of lines hold >=1 token), cutting
// HBM fetch from 512 MB (one line per (e,token)) to ~190 MB.

#define VOCAB 50257
#define EMBED 1024
#define NTOK  4096
#define THREADS 256
#define VTILE (THREADS * 4)                       // 1024 vocab entries / block
#define NVSTRIPS ((VOCAB + VTILE - 1) / VTILE)    // 50
#define ETILE 32                                  // 32 e-rows / block = one 128B out-line per token
#define NETILES (EMBED / ETILE)                   // 32

// ws layout: first_pos[50432 (padded)] , nxt[4096]
#define FP_PAD 50432

__global__ __launch_bounds__(THREADS) void init_map_kernel(int* __restrict__ first_pos) {
    const int v = blockIdx.x * THREADS + threadIdx.x;
    if (v < VOCAB) first_pos[v] = -1;
}

__global__ __launch_bounds__(THREADS) void build_map_kernel(const int* __restrict__ tokens,
                                                            int* __restrict__ first_pos,
                                                            int* __restrict__ nxt) {
    const int pos = blockIdx.x * THREADS + threadIdx.x;
    if (pos < NTOK) {
        // chain of positions per vocab id; order is atomic-race-dependent but
        // the OUTPUT is order-independent (every pos gets the same column).
        nxt[pos] = atomicExch(&first_pos[tokens[pos]], pos);
    }
}

__global__ __launch_bounds__(THREADS) void scatter_kernel(
    const float* __restrict__ W,
    const int* __restrict__ first_pos,
    const int* __restrict__ nxt,
    float* __restrict__ out) {
    const int strip = (int)blockIdx.x / NETILES;
    const int etile = (int)blockIdx.x % NETILES;
    const int v0 = strip * VTILE + (int)threadIdx.x * 4;
    const int e0 = etile * ETILE;

    int fp[4];
#pragma unroll
    for (int j = 0; j < 4; ++j) {
        const int v = v0 + j;
        fp[j] = (v < VOCAB) ? first_pos[v] : -1;
    }
    // all-(-1) AND stays -1; any hit (MSB=0) clears the sign bit
    if ((fp[0] & fp[1] & fp[2] & fp[3]) == -1) return;

    const float* __restrict__ Wbase = W + (size_t)e0 * VOCAB + v0;
#pragma unroll 4
    for (int ei = 0; ei < ETILE; ++ei) {
        const int e = e0 + ei;
        const float* __restrict__ Wrow = Wbase + (size_t)ei * VOCAB;
#pragma unroll
        for (int j = 0; j < 4; ++j) {
            int p = fp[j];
            if (p >= 0) {
                const float x = Wrow[j];       // only hit elements are loaded
                do {
                    out[(size_t)p * EMBED + e] = x;   // 32 e's = one full 128B line
                    p = nxt[p];                        // duplicates (~4%) via chain
                } while (p >= 0);
            }
        }
    }
}

extern "C" void kernel_launch(void* const* d_in, const int* in_sizes, int n_in,
                              void* d_out, int out_size, void* d_ws, size_t ws_size,
                              hipStream_t stream) {
    const int*   tokens = (const int*)d_in[0];   // (4096,) int32
    const float* W      = (const float*)d_in[1]; // (1024, 50257) fp32
    float*       out    = (float*)d_out;         // (4096, 1024) fp32

    int* first_pos = (int*)d_ws;                 // 50257 ints (padded to 50432)
    int* nxt       = first_pos + FP_PAD;         // 4096 ints

    init_map_kernel<<<(VOCAB + THREADS - 1) / THREADS, THREADS, 0, stream>>>(first_pos);
    build_map_kernel<<<NTOK / THREADS, THREADS, 0, stream>>>(tokens, first_pos, nxt);
    scatter_kernel<<<NVSTRIPS * NETILES, THREADS, 0, stream>>>(W, first_pos, nxt, out);
}

// Round 3
// 58.416 us; speedup vs baseline: 1.9346x; 1.9346x over previous
//
#include <hip/hip_runtime.h>

// out[pos,e] = W[e, tokens[pos]]  (one_hot @ W.T == embedding gather).
// Two-phase: (1) compact the ~3933 unique columns of W into dense C[rank][e]
// with vocab-adjacent reads (needed elements share HBM lines) and 64B-aligned
// contiguous writes; (2) coalesced gather out[pos] = C[rank[tokens[pos]]].

#define VOCAB 50257
#define EMBED 1024
#define NTOK  4096
#define NW    1571            // ceil(VOCAB/32) mask words
#define NW_PAD 2048
#define VTILE 1024            // vocab span per compact block (256 thr * 4)
#define NVSTRIPS 50           // ceil(50257/1024)
#define ETILE 16              // e-rows per compact block; 16*4B = 64B chunk
#define NETILES (EMBED / ETILE)   // 64

__global__ __launch_bounds__(256) void zero_mask_kernel(unsigned int* __restrict__ mask) {
    const int i = blockIdx.x * 256 + threadIdx.x;
    if (i < NW_PAD) mask[i] = 0u;
}

__global__ __launch_bounds__(256) void mark_kernel(const int* __restrict__ tokens,
                                                   unsigned int* __restrict__ mask) {
    const int pos = blockIdx.x * 256 + threadIdx.x;
    if (pos < NTOK) {
        const int t = tokens[pos];
        atomicOr(&mask[t >> 5], 1u << (t & 31));
    }
}

// Exclusive scan of per-word popcounts -> word_base[w] = #present ids before word w.
// Deterministic (rank = position in sorted unique-vocab order).
__global__ __launch_bounds__(1024) void scan_kernel(const unsigned int* __restrict__ mask,
                                                    int* __restrict__ word_base) {
    const int t = threadIdx.x;
    const unsigned int w0 = mask[2 * t], w1 = mask[2 * t + 1];
    const int c0 = __popc(w0), c1 = __popc(w1);
    const int sum = c0 + c1;
    const int lane = t & 63, wid = t >> 6;
    int inc = sum;
#pragma unroll
    for (int d = 1; d < 64; d <<= 1) {
        const int u = __shfl_up(inc, d, 64);
        if (lane >= d) inc += u;
    }
    __shared__ int wsum[16];
    if (lane == 63) wsum[wid] = inc;
    __syncthreads();
    if (t == 0) {
        int acc = 0;
#pragma unroll
        for (int i = 0; i < 16; ++i) { const int v = wsum[i]; wsum[i] = acc; acc += v; }
    }
    __syncthreads();
    const int excl = wsum[wid] + inc - sum;   // exclusive prefix for this thread
    word_base[2 * t]     = excl;
    word_base[2 * t + 1] = excl + c0;
}

__global__ __launch_bounds__(256) void compact_kernel(
    const float* __restrict__ W,
    const unsigned int* __restrict__ mask,
    const int* __restrict__ word_base,
    float* __restrict__ C) {
    const int strip = (int)blockIdx.x / NETILES;
    const int etile = (int)blockIdx.x % NETILES;
    const int v0 = strip * VTILE + (int)threadIdx.x * 4;   // 4 consecutive v per lane
    const int e0 = etile * ETILE;

    const int w = v0 >> 5;
    const unsigned int m = mask[w];                        // padded words are 0 -> v>=VOCAB safe
    const unsigned int bits = (m >> (v0 & 31)) & 0xFu;
    if (!bits) return;
    const int base = word_base[w] + __popc(m & ((1u << (v0 & 31)) - 1u));

#pragma unroll
    for (int j = 0; j < 4; ++j) {
        if ((bits >> j) & 1u) {
            const int r = base + __popc(bits & ((1u << j) - 1u));
            const float* __restrict__ src = W + (size_t)e0 * VOCAB + v0 + j;
            float* __restrict__ dst = C + (size_t)r * EMBED + e0;   // 64B-aligned chunk
#pragma unroll
            for (int ei = 0; ei < ETILE; ++ei)
                dst[ei] = src[(size_t)ei * VOCAB];
        }
    }
}

__global__ __launch_bounds__(256) void gather_out_kernel(
    const int* __restrict__ tokens,
    const unsigned int* __restrict__ mask,
    const int* __restrict__ word_base,
    const float* __restrict__ C,
    float* __restrict__ out) {
    const int pos = blockIdx.x;
    const int t = tokens[pos];
    const unsigned int m = mask[t >> 5];
    const int r = word_base[t >> 5] + __popc(m & ((1u << (t & 31)) - 1u));
    const int e = (int)threadIdx.x * 4;
    const float4 v = *reinterpret_cast<const float4*>(C + (size_t)r * EMBED + e);
    *reinterpret_cast<float4*>(out + (size_t)pos * EMBED + e) = v;
}

// Fallback (R1 kernel) if the workspace is too small for C.
__global__ __launch_bounds__(256) void embed_gather_kernel(
    const int* __restrict__ tokens,
    const float* __restrict__ W,
    float* __restrict__ out) {
    const int pos = blockIdx.x;
    const int t = tokens[pos];
    const int e0 = (int)threadIdx.x * 4;
    const float* __restrict__ col = W + t;
    float4 v;
    v.x = col[(size_t)(e0 + 0) * VOCAB];
    v.y = col[(size_t)(e0 + 1) * VOCAB];
    v.z = col[(size_t)(e0 + 2) * VOCAB];
    v.w = col[(size_t)(e0 + 3) * VOCAB];
    *reinterpret_cast<float4*>(out + (size_t)pos * EMBED + e0) = v;
}

extern "C" void kernel_launch(void* const* d_in, const int* in_sizes, int n_in,
                              void* d_out, int out_size, void* d_ws, size_t ws_size,
                              hipStream_t stream) {
    const int*   tokens = (const int*)d_in[0];   // (4096,) int32
    const float* W      = (const float*)d_in[1]; // (1024, 50257) fp32
    float*       out    = (float*)d_out;         // (4096, 1024) fp32

    const size_t need = (size_t)NW_PAD * 4 * 2 + (size_t)NTOK * EMBED * 4;
    if (ws_size < need) {
        embed_gather_kernel<<<NTOK, 256, 0, stream>>>(tokens, W, out);
        return;
    }

    unsigned int* mask      = (unsigned int*)d_ws;            // 8 KB
    int*          word_base = (int*)(mask + NW_PAD);          // 8 KB
    float*        C         = (float*)(word_base + NW_PAD);   // up to 16 MB

    zero_mask_kernel<<<NW_PAD / 256, 256, 0, stream>>>(mask);
    mark_kernel<<<NTOK / 256, 256, 0, stream>>>(tokens, mask);
    scan_kernel<<<1, 1024, 0, stream>>>(mask, word_base);
    compact_kernel<<<NVSTRIPS * NETILES, 256, 0, stream>>>(W, mask, word_base, C);
    gather_out_kernel<<<NTOK, 256, 0, stream>>>(tokens, mask, word_base, C, out);
}

// Round 4
// 56.616 us; speedup vs baseline: 1.9961x; 1.0318x over previous
//
#include <hip/hip_runtime.h>

// out[pos,e] = W[e, tokens[pos]]  (one_hot @ W.T == embedding gather).
// R4: two kernels.
//  setup  (1 block): LDS mask over vocab -> block scan -> rank per unique id;
//                    duplicate chains rep[rank] / nxt[pos] via LDS atomicExch.
//  compact(3200 blk): vocab-strip x e-tile; reads only W sectors containing a
//                    present token (~96 MB @32B sectors), writes straight to
//                    out via chain walk in 64B float4 chunks. No C round trip.

#define VOCAB 50257
#define EMBED 1024
#define NTOK  4096
#define NWPAD 2048            // padded mask words (>= ceil(50257/32)=1571)
#define VTILE 1024            // vocab span per compact block (256 thr * 4)
#define NVSTRIPS 50           // ceil(50257/1024)
#define ETILE 16              // e-rows per compact block; 16*4B = 64B chunk
#define NETILES (EMBED / ETILE)   // 64

__global__ __launch_bounds__(1024) void setup_kernel(
    const int* __restrict__ tokens,
    unsigned int* __restrict__ g_mask,   // [NWPAD]
    int* __restrict__ g_wb,              // [NWPAD]
    int* __restrict__ g_rep,             // [NTOK] head pos per rank
    int* __restrict__ g_nxt) {           // [NTOK] chain
    __shared__ unsigned int mask[NWPAD];
    __shared__ int wb[NWPAD];
    __shared__ int rep[NTOK];
    __shared__ int nxt[NTOK];
    __shared__ int wsum[16];
    const int t = threadIdx.x;

    mask[t] = 0u; mask[t + 1024] = 0u;
    rep[t] = -1; rep[t + 1024] = -1; rep[t + 2048] = -1; rep[t + 3072] = -1;
    __syncthreads();

    // mark
    const int4 tk = reinterpret_cast<const int4*>(tokens)[t];  // 4 tokens/thread
    atomicOr(&mask[tk.x >> 5], 1u << (tk.x & 31));
    atomicOr(&mask[tk.y >> 5], 1u << (tk.y & 31));
    atomicOr(&mask[tk.z >> 5], 1u << (tk.z & 31));
    atomicOr(&mask[tk.w >> 5], 1u << (tk.w & 31));
    __syncthreads();

    // exclusive scan of per-word popcounts (2 words/thread)
    const unsigned int w0 = mask[2 * t], w1 = mask[2 * t + 1];
    const int c0 = __popc(w0), c1 = __popc(w1);
    const int sum = c0 + c1;
    const int lane = t & 63, wid = t >> 6;
    int inc = sum;
#pragma unroll
    for (int d = 1; d < 64; d <<= 1) {
        const int u = __shfl_up(inc, d, 64);
        if (lane >= d) inc += u;
    }
    if (lane == 63) wsum[wid] = inc;
    __syncthreads();
    if (t == 0) {
        int acc = 0;
#pragma unroll
        for (int i = 0; i < 16; ++i) { const int v = wsum[i]; wsum[i] = acc; acc += v; }
    }
    __syncthreads();
    const int excl = wsum[wid] + inc - sum;
    wb[2 * t] = excl;
    wb[2 * t + 1] = excl + c0;
    __syncthreads();

    // duplicate chains: rank -> chain of positions (order race-dependent,
    // output content order-independent: all chain members get the same row)
#pragma unroll
    for (int j = 0; j < 4; ++j) {
        const int pos = t * 4 + j;
        const int tok = (j == 0) ? tk.x : (j == 1) ? tk.y : (j == 2) ? tk.z : tk.w;
        const unsigned int m = mask[tok >> 5];
        const int r = wb[tok >> 5] + __popc(m & ((1u << (tok & 31)) - 1u));
        nxt[pos] = atomicExch(&rep[r], pos);
    }
    __syncthreads();

    // export
    g_mask[t] = mask[t]; g_mask[t + 1024] = mask[t + 1024];
    g_wb[t] = wb[t];     g_wb[t + 1024] = wb[t + 1024];
    g_rep[t] = rep[t]; g_rep[t + 1024] = rep[t + 1024];
    g_rep[t + 2048] = rep[t + 2048]; g_rep[t + 3072] = rep[t + 3072];
    g_nxt[t] = nxt[t]; g_nxt[t + 1024] = nxt[t + 1024];
    g_nxt[t + 2048] = nxt[t + 2048]; g_nxt[t + 3072] = nxt[t + 3072];
}

__global__ __launch_bounds__(256) void compact_kernel(
    const float* __restrict__ W,
    const unsigned int* __restrict__ mask,
    const int* __restrict__ wb,
    const int* __restrict__ rep,
    const int* __restrict__ nxt,
    float* __restrict__ out) {
    const int strip = (int)blockIdx.x / NETILES;
    const int etile = (int)blockIdx.x % NETILES;
    const int v0 = strip * VTILE + (int)threadIdx.x * 4;   // 4 consecutive v per lane
    const int e0 = etile * ETILE;

    const int w = v0 >> 5;
    const unsigned int m = mask[w];                        // padded words are 0
    const unsigned int bits = (m >> (v0 & 31)) & 0xFu;
    if (!bits) return;
    const int base = wb[w] + __popc(m & ((1u << (v0 & 31)) - 1u));

#pragma unroll
    for (int j = 0; j < 4; ++j) {
        if ((bits >> j) & 1u) {
            const int r = base + __popc(bits & ((1u << j) - 1u));
            const float* __restrict__ src = W + (size_t)e0 * VOCAB + v0 + j;
            float4 val[4];
#pragma unroll
            for (int q = 0; q < 4; ++q) {
                val[q].x = src[(size_t)(4 * q + 0) * VOCAB];
                val[q].y = src[(size_t)(4 * q + 1) * VOCAB];
                val[q].z = src[(size_t)(4 * q + 2) * VOCAB];
                val[q].w = src[(size_t)(4 * q + 3) * VOCAB];
            }
            int p = rep[r];
            do {
                float4* __restrict__ dst =
                    reinterpret_cast<float4*>(out + (size_t)p * EMBED + e0);
#pragma unroll
                for (int q = 0; q < 4; ++q) dst[q] = val[q];   // 64B contiguous
                p = nxt[p];
            } while (p >= 0);
        }
    }
}

// Fallback (R1 kernel) if the workspace is too small.
__global__ __launch_bounds__(256) void embed_gather_kernel(
    const int* __restrict__ tokens,
    const float* __restrict__ W,
    float* __restrict__ out) {
    const int pos = blockIdx.x;
    const int tok = tokens[pos];
    const int e0 = (int)threadIdx.x * 4;
    const float* __restrict__ col = W + tok;
    float4 v;
    v.x = col[(size_t)(e0 + 0) * VOCAB];
    v.y = col[(size_t)(e0 + 1) * VOCAB];
    v.z = col[(size_t)(e0 + 2) * VOCAB];
    v.w = col[(size_t)(e0 + 3) * VOCAB];
    *reinterpret_cast<float4*>(out + (size_t)pos * EMBED + e0) = v;
}

extern "C" void kernel_launch(void* const* d_in, const int* in_sizes, int n_in,
                              void* d_out, int out_size, void* d_ws, size_t ws_size,
                              hipStream_t stream) {
    const int*   tokens = (const int*)d_in[0];   // (4096,) int32
    const float* W      = (const float*)d_in[1]; // (1024, 50257) fp32
    float*       out    = (float*)d_out;         // (4096, 1024) fp32

    const size_t need = (size_t)(NWPAD * 2 + NTOK * 2) * 4;  // 48 KB
    if (ws_size < need) {
        embed_gather_kernel<<<NTOK, 256, 0, stream>>>(tokens, W, out);
        return;
    }

    unsigned int* mask = (unsigned int*)d_ws;    // 8 KB
    int* wb  = (int*)(mask + NWPAD);             // 8 KB
    int* rep = wb + NWPAD;                       // 16 KB
    int* nxt = rep + NTOK;                       // 16 KB

    setup_kernel<<<1, 1024, 0, stream>>>(tokens, mask, wb, rep, nxt);
    compact_kernel<<<NVSTRIPS * NETILES, 256, 0, stream>>>(W, mask, wb, rep, nxt, out);
}